// Round 1
// baseline (76.004 us; speedup 1.0000x reference)
//
#include <hip/hip_runtime.h>

// loss = sum over flows/channels of mean_{b,h,w} || (I - P_A) patch ||^2
// P_A projects onto affine functions of patch offsets (a, c); the coordinate
// grids added in the reference are affine in (a,c) -> annihilated, so we can
// work on the raw flow channels.
// Residual via orthonormal basis: r = sumsq - sum^2/kz^2 - (sa^2 + sc^2)/S,
//   sa = sum (a-m) p, sc = sum (c-m) p, m = (kz-1)/2, S = kz * sum_t (t-m)^2.
//
// v2 structure: separable row statistics + vertical strip reuse.
//   Each thread owns VX=2 output columns (aligned float2 loads) and STRIP=7
//   output rows. Per input row it computes (rowsum, rowsumsq, row c-moment)
//   once into a KZ-deep rolling register buffer; each output row combines KZ
//   row-stat triples. Loads drop ~10x, VALU ~2.5x vs per-output KZ^2 loop.
//   W is a template parameter so all div/mod fold to magic multiplies.

template<int KZ, int W, int STRIP>
__device__ __forceinline__ float patch_strip_acc(const float* __restrict__ flow,
                                                 int nitems, int bid, int nblocks) {
    constexpr int Wout   = W - KZ + 1;
    constexpr int XB     = Wout / 2;        // thread-columns (VX=2)
    constexpr int NSTRIP = Wout / STRIP;    // exact: 126/7=18, 252/7=36
    constexpr int ROWS   = STRIP + KZ - 1;  // input rows touched per strip
    const float m = (KZ - 1) * 0.5f;

    float Ssum = 0.f;
#pragma unroll
    for (int t = 0; t < KZ; ++t) Ssum += (t - m) * (t - m);
    const float invS  = 1.0f / (Ssum * KZ);
    const float invk2 = 1.0f / (KZ * KZ);

    float acc = 0.f;
    for (int item = bid * blockDim.x + threadIdx.x; item < nitems;
         item += nblocks * blockDim.x) {
        // item -> (xb fastest for coalescing, strip, bc); divisors constexpr
        int xb = item % XB;
        int t1 = item / XB;
        int ys = (t1 % NSTRIP) * STRIP;
        int bc = t1 / NSTRIP;               // b*2 + channel
        const float* base = flow + (size_t)bc * (W * W) + (size_t)ys * W + xb * 2;

        float rsb[KZ][2];   // rolling row sums
        float rssb[KZ][2];  // rolling row sum-of-squares
        float rscb[KZ][2];  // rolling row c-moments
#pragma unroll
        for (int r = 0; r < ROWS; ++r) {
            const float* rowp = base + r * W;
            float v[KZ + 1];
#pragma unroll
            for (int c2 = 0; c2 < (KZ + 1) / 2; ++c2) {
                float2 u = *reinterpret_cast<const float2*>(rowp + 2 * c2);
                v[2 * c2]     = u.x;
                v[2 * c2 + 1] = u.y;
            }
            const int slot = r % KZ;        // compile-time after full unroll
#pragma unroll
            for (int j = 0; j < 2; ++j) {
                float rs = 0.f, rss = 0.f, rsc = 0.f;
#pragma unroll
                for (int c = 0; c < KZ; ++c) {
                    float p = v[j + c];
                    rs  += p;
                    rss += p * p;
                    rsc += (c - m) * p;
                }
                rsb[slot][j]  = rs;
                rssb[slot][j] = rss;
                rscb[slot][j] = rsc;
            }
            if (r >= KZ - 1) {              // constant per unrolled iteration
                const int y = r - (KZ - 1);
#pragma unroll
                for (int j = 0; j < 2; ++j) {
                    float sum = 0.f, sumsq = 0.f, sa = 0.f, sc = 0.f;
#pragma unroll
                    for (int a = 0; a < KZ; ++a) {
                        const int s = (y + a) % KZ;   // compile-time
                        sum   += rsb[s][j];
                        sumsq += rssb[s][j];
                        sa    += (a - m) * rsb[s][j];
                        sc    += rscb[s][j];
                    }
                    acc += sumsq - sum * sum * invk2 - (sa * sa + sc * sc) * invS;
                }
            }
        }
    }
    return acc;
}

__global__ __launch_bounds__(256) void fused_patch_loss(
        const float* __restrict__ flow0, const float* __restrict__ flow1,
        int nb0, int ni0, int ni1, float s0, float s1,
        float* __restrict__ partial) {
    float acc;
    if ((int)blockIdx.x < nb0) {
        acc = s0 * patch_strip_acc<3, 128, 7>(flow0, ni0, blockIdx.x, nb0);
    } else {
        acc = s1 * patch_strip_acc<5, 256, 7>(flow1, ni1, blockIdx.x - nb0,
                                              gridDim.x - nb0);
    }
    // block reduction: 64-lane shuffle then LDS across 4 waves
    for (int off = 32; off > 0; off >>= 1) acc += __shfl_down(acc, off);
    __shared__ float red[4];
    int lane = threadIdx.x & 63;
    int wid  = threadIdx.x >> 6;
    if (lane == 0) red[wid] = acc;
    __syncthreads();
    if (threadIdx.x == 0)
        partial[blockIdx.x] = red[0] + red[1] + red[2] + red[3];
}

__global__ void final_reduce_kernel(const float* __restrict__ partial, int n,
                                    float* __restrict__ out) {
    float acc = 0.f;
    for (int i = threadIdx.x; i < n; i += blockDim.x) acc += partial[i];
    for (int off = 32; off > 0; off >>= 1) acc += __shfl_down(acc, off);
    __shared__ float red[4];
    int lane = threadIdx.x & 63;
    int wid  = threadIdx.x >> 6;
    if (lane == 0) red[wid] = acc;
    __syncthreads();
    if (threadIdx.x == 0) out[0] = red[0] + red[1] + red[2] + red[3];
}

extern "C" void kernel_launch(void* const* d_in, const int* in_sizes, int n_in,
                              void* d_out, int out_size, void* d_ws, size_t ws_size,
                              hipStream_t stream) {
    const float* flow0 = (const float*)d_in[0];   // (32, 2, 128, 128)
    const float* flow1 = (const float*)d_in[1];   // (32, 2, 256, 256)
    float* out = (float*)d_out;
    float* partial = (float*)d_ws;

    // flow0: kz=3, W=128, Wout=126: items = (126/2) * (126/7) * 64 = 72,576
    // flow1: kz=5, W=256, Wout=252: items = (252/2) * (252/7) * 64 = 290,304
    const int ni0 = 63 * 18 * 64;
    const int ni1 = 126 * 36 * 64;
    const int nb0 = (ni0 + 255) / 256;            // 284
    const int nb1 = ni1 / 256;                    // 1134 (exact)
    const int nbt = nb0 + nb1;                    // 1418

    const float s0 = 1.0f / (32.0f * 126.0f * 126.0f);
    const float s1 = 1.0f / (32.0f * 252.0f * 252.0f);

    fused_patch_loss<<<nbt, 256, 0, stream>>>(flow0, flow1, nb0, ni0, ni1,
                                              s0, s1, partial);
    final_reduce_kernel<<<1, 256, 0, stream>>>(partial, nbt, out);
}